// Round 6
// baseline (1646.674 us; speedup 1.0000x reference)
//
#include <hip/hip_runtime.h>
#include <hip/hip_bf16.h>
#include <stdint.h>

// ---------------------------------------------------------------------------
// EncodeProcessDecode (MeshGraphNets) on MI355X — Round 6:
//  * e16 stream dropped (staging converts e32 -> bf16 on load; bit-identical)
//  * csr_agg fused into node kernel as LDS prepass (same sum order)
//  * node/decoder use BM=64 (grid 157) via RT template param
//  * register-prefetch software pipeline in all GEMM layers
//
#define N_NODES 10000
#define N_EDGES 80000
#define L 128
#define STEPS 15
#define LN_EPS 1e-5f
#define NTHR 256
#define H_STRIDE 272

typedef short short8 __attribute__((ext_vector_type(8)));
typedef float floatx4 __attribute__((ext_vector_type(4)));

__device__ __forceinline__ float bf2f(const __hip_bfloat16 x) {
    return __bfloat162float(x);
}
__device__ __forceinline__ float ldmix(const void* p, int idx, int isf32) {
    return isf32 ? ((const float*)p)[idx]
                 : bf2f(((const __hip_bfloat16*)p)[idx]);
}

// ---------------------------------------------------------------------------
__global__ void detect_dtype(const uint32_t* __restrict__ nf, int* cnt) {
    int c = 0;
    for (int i = blockIdx.x * blockDim.x + threadIdx.x; i < 60000;
         i += gridDim.x * blockDim.x) {
        const uint32_t w = nf[i];
        c += (((w >> 7) & 0xFF) >= 0xC6) + (((w >> 23) & 0xFF) >= 0xC6);
    }
    atomicAdd(cnt, c);
}

// ---------------------------------------------------------------------------
#define N_TMATS 14
struct TAll {
    const void* src[N_TMATS];
    long long cum[N_TMATS + 1];
    int K[N_TMATS], N[N_TMATS], Kpad[N_TMATS];
};

__global__ void transpose_all(TAll a, const int* __restrict__ cnt,
                              __hip_bfloat16* __restrict__ pool) {
    const int isf32 = (*cnt > 1000);
    const long long total = a.cum[N_TMATS];
    for (long long i = blockIdx.x * (long long)blockDim.x + threadIdx.x;
         i < total; i += gridDim.x * (long long)blockDim.x) {
        int e = 0;
        #pragma unroll 1
        for (int j = 1; j < N_TMATS; j++) if (i >= a.cum[j]) e = j;
        const long long r = i - a.cum[e];
        const int per = a.N[e] * a.Kpad[e];
        const int m = (int)(r / per);
        const int r2 = (int)(r - (long long)m * per);
        const int nn = r2 / a.Kpad[e];
        const int kk = r2 - nn * a.Kpad[e];
        float v = 0.f;
        if (kk < a.K[e]) v = ldmix(a.src[e], (m * a.K[e] + kk) * a.N[e] + nn, isf32);
        pool[i] = __float2bfloat16(v);
    }
}

__global__ void convert_feats(const void* __restrict__ nf,
                              const void* __restrict__ ef,
                              const int* __restrict__ cnt,
                              __hip_bfloat16* __restrict__ fN,
                              __hip_bfloat16* __restrict__ fE)
{
    const int isf32 = (*cnt > 1000);
    const int totN = N_NODES * 32;
    const int totE = N_EDGES * 32;
    for (int i = blockIdx.x * blockDim.x + threadIdx.x; i < totN + totE;
         i += gridDim.x * blockDim.x) {
        if (i < totN) {
            const int r = i >> 5, c = i & 31;
            fN[i] = __float2bfloat16(c < 12 ? ldmix(nf, r * 12 + c, isf32) : 0.f);
        } else {
            const int j = i - totN;
            const int r = j >> 5, c = j & 31;
            fE[j] = __float2bfloat16(c < 7 ? ldmix(ef, r * 7 + c, isf32) : 0.f);
        }
    }
}

// ---------------------------------------------------------------------------
// CSR build (receiver lists)
__global__ void csr_hist(const int* __restrict__ rcv, int* __restrict__ deg) {
    for (int i = blockIdx.x * blockDim.x + threadIdx.x; i < N_EDGES;
         i += gridDim.x * blockDim.x)
        atomicAdd(&deg[rcv[i]], 1);
}

__global__ void csr_scan(const int* __restrict__ deg, int* __restrict__ rowptr,
                         int* __restrict__ cursor) {
    __shared__ int part[256];
    __shared__ int partx[257];
    const int t = threadIdx.x;
    int s = 0;
    for (int j = 0; j < 40; j++) {
        const int i = t * 40 + j;
        if (i < N_NODES) s += deg[i];
    }
    part[t] = s;
    __syncthreads();
    if (t == 0) {
        int r = 0;
        for (int k = 0; k < 256; k++) { partx[k] = r; r += part[k]; }
        partx[256] = r;
    }
    __syncthreads();
    int run = partx[t];
    for (int j = 0; j < 40; j++) {
        const int i = t * 40 + j;
        if (i < N_NODES) {
            rowptr[i] = run;
            cursor[i] = run;
            run += deg[i];
        }
    }
    if (t == 255) rowptr[N_NODES] = partx[256];
}

__global__ void csr_scatter(const int* __restrict__ rcv, int* __restrict__ cursor,
                            int* __restrict__ elist) {
    for (int i = blockIdx.x * blockDim.x + threadIdx.x; i < N_EDGES;
         i += gridDim.x * blockDim.x) {
        const int p = atomicAdd(&cursor[rcv[i]], 1);
        elist[p] = i;
    }
}

// ---------------------------------------------------------------------------
enum AMode { A_PLAIN = 0, A_FEAT = 1, A_CAT = 2 };
enum Epi   { E_LN_STORE = 0, E_LN_EDGE = 1, E_LN_NODE = 2, E_DEC = 3 };

// Fused NL-layer MLP. Block: BMv = 64*RT rows x 128 cols, 4 waves; wave w owns
// rows [w*16*RT, (w+1)*16*RT). A_CAT computes agg in an LDS prepass from CSR.
template <int AMODE, int EPI, int NL, int RT>
__global__ __launch_bounds__(NTHR, 2)
void fused_mlp(const __hip_bfloat16* __restrict__ A, int lda, int M, int K0,
               const __hip_bfloat16* __restrict__ WT0,
               const __hip_bfloat16* __restrict__ WT1,
               const __hip_bfloat16* __restrict__ WT2,
               const void* __restrict__ b0,
               const void* __restrict__ b1,
               const void* __restrict__ b2,
               const void* __restrict__ g,
               const void* __restrict__ beta,
               int poff,
               const int* __restrict__ cnt,
               const __hip_bfloat16* n16,        // gathers / A_CAT region 0
               const __hip_bfloat16* lnsrc,      // A_CAT prepass: ln16
               const int* __restrict__ snd,
               const int* __restrict__ rcv,
               const int* __restrict__ rowptr,
               const int* __restrict__ elist,
               float* res32,                     // residual f32 (also A_FEAT e src)
               __hip_bfloat16* res16,            // optional bf16 residual copy
               __hip_bfloat16* __restrict__ lnout, // E_LN_EDGE: ln16 out
               const void* __restrict__ dW,
               const void* __restrict__ db,
               void* __restrict__ dout)
{
    constexpr int BMv   = 64 * RT;
    constexpr int HW    = RT * 16 * H_STRIDE;       // per-wave h bytes
    constexpr int WSOFF = 4 * HW;
    constexpr int LDSB  = WSOFF + 10240 + ((AMODE == A_CAT) ? BMv * 256 : 0);
    __shared__ __align__(16) char lds[LDSB];
    char* AsB = lds;                 // layer-0 A staging (overlaps h region)
    char* WsB = lds + WSOFF;         // W staging
    char* AgL = lds + WSOFF + 10240; // A_CAT agg (bf16, 256 B/row)

    const int tid  = threadIdx.x;
    const int wv   = tid >> 6;
    const int lane = tid & 63;
    const int quad = lane >> 4;
    const int m15  = lane & 15;
    const int row0 = blockIdx.x * BMv;
    const int isf32 = (*cnt > 1000);

    char* hw = lds + wv * HW;

    const int boff = m15 * 80 + quad * 16;
    int aoff[RT];
    #pragma unroll
    for (int rt = 0; rt < RT; rt++)
        aoff[rt] = (wv * 16 * RT + rt * 16 + m15) * 80 + quad * 16;

    // -------- A_CAT prepass: agg for this block's rows into AgL --------
    if constexpr (AMODE == A_CAT) {
        const int half = tid >> 5, hl = tid & 31;
        for (int v = half; v < BMv; v += 8) {
            const int rg = row0 + v;
            float s0 = 0.f, s1 = 0.f, s2 = 0.f, s3 = 0.f;
            if (rg < M) {
                int j = rowptr[rg];
                const int en = rowptr[rg + 1];
                for (; j + 3 < en; j += 4) {
                    const int e0 = elist[j], e1 = elist[j+1], e2 = elist[j+2], e3 = elist[j+3];
                    union { uint2 w; __hip_bfloat16 h[4]; } u0, u1, u2, u3;
                    u0.w = *(const uint2*)(lnsrc + (size_t)e0 * L + hl * 4);
                    u1.w = *(const uint2*)(lnsrc + (size_t)e1 * L + hl * 4);
                    u2.w = *(const uint2*)(lnsrc + (size_t)e2 * L + hl * 4);
                    u3.w = *(const uint2*)(lnsrc + (size_t)e3 * L + hl * 4);
                    s0 += bf2f(u0.h[0]); s1 += bf2f(u0.h[1]); s2 += bf2f(u0.h[2]); s3 += bf2f(u0.h[3]);
                    s0 += bf2f(u1.h[0]); s1 += bf2f(u1.h[1]); s2 += bf2f(u1.h[2]); s3 += bf2f(u1.h[3]);
                    s0 += bf2f(u2.h[0]); s1 += bf2f(u2.h[1]); s2 += bf2f(u2.h[2]); s3 += bf2f(u2.h[3]);
                    s0 += bf2f(u3.h[0]); s1 += bf2f(u3.h[1]); s2 += bf2f(u3.h[2]); s3 += bf2f(u3.h[3]);
                }
                for (; j < en; j++) {
                    const int e = elist[j];
                    union { uint2 w; __hip_bfloat16 h[4]; } u;
                    u.w = *(const uint2*)(lnsrc + (size_t)e * L + hl * 4);
                    s0 += bf2f(u.h[0]); s1 += bf2f(u.h[1]); s2 += bf2f(u.h[2]); s3 += bf2f(u.h[3]);
                }
            }
            union { uint2 w; __hip_bfloat16 h[4]; } o;
            o.h[0] = __float2bfloat16(s0); o.h[1] = __float2bfloat16(s1);
            o.h[2] = __float2bfloat16(s2); o.h[3] = __float2bfloat16(s3);
            *(uint2*)(AgL + v * 256 + hl * 8) = o.w;
        }
        __syncthreads();
    }

    // staging assignments (fixed per thread)
    const int aq = tid & 3;
    int arow[RT], sidx[RT], ridx[RT];
    #pragma unroll
    for (int i2 = 0; i2 < RT; i2++) {
        arow[i2] = (i2 * NTHR + tid) >> 2;
        if constexpr (AMODE == A_FEAT) {
            const int rg = row0 + arow[i2];
            sidx[i2] = (rg < M) ? snd[rg] : 0;
            ridx[i2] = (rg < M) ? rcv[rg] : 0;
        }
    }

    auto loadA = [&](int k0, int i2) -> int4 {
        const int ar = arow[i2];
        const int rg = row0 + ar;
        int4 av = make_int4(0, 0, 0, 0);
        if (rg < M) {
            if constexpr (AMODE == A_PLAIN) {
                av = *(const int4*)(A + (size_t)rg * lda + k0 + aq * 8);
            } else if constexpr (AMODE == A_FEAT) {
                if (k0 < 2 * L) {
                    const int nd = (k0 < L) ? sidx[i2] : ridx[i2];
                    av = *(const int4*)(n16 + (size_t)nd * L + (k0 & (L - 1)) + aq * 8);
                } else {
                    const float* sp = res32 + (size_t)rg * L + (k0 - 2 * L) + aq * 8;
                    const float4 f0 = *(const float4*)sp;
                    const float4 f1 = *(const float4*)(sp + 4);
                    union { int4 v; __hip_bfloat16 h[8]; } u;
                    u.h[0] = __float2bfloat16(f0.x); u.h[1] = __float2bfloat16(f0.y);
                    u.h[2] = __float2bfloat16(f0.z); u.h[3] = __float2bfloat16(f0.w);
                    u.h[4] = __float2bfloat16(f1.x); u.h[5] = __float2bfloat16(f1.y);
                    u.h[6] = __float2bfloat16(f1.z); u.h[7] = __float2bfloat16(f1.w);
                    av = u.v;
                }
            } else { // A_CAT
                if (k0 < L) av = *(const int4*)(n16 + (size_t)rg * L + k0 + aq * 8);
                else        av = *(const int4*)(AgL + ar * 256 + (k0 - L) * 2 + aq * 16);
            }
        }
        return av;
    };
    auto loadW = [&](const __hip_bfloat16* WT, int ksz, int k0, int i2) -> int4 {
        const int flat = i2 * NTHR + tid;
        return *(const int4*)(WT + (size_t)(flat >> 2) * ksz + k0 + (flat & 3) * 8);
    };

    floatx4 acc[RT][8];

    // ===================== layer 0 (reg-prefetch pipeline) =====================
    #pragma unroll
    for (int rt = 0; rt < RT; rt++)
        #pragma unroll
        for (int ct = 0; ct < 8; ct++) acc[rt][ct] = (floatx4)0.f;

    int4 pA[RT], pW[2];
    #pragma unroll
    for (int i2 = 0; i2 < RT; i2++) pA[i2] = loadA(0, i2);
    pW[0] = loadW(WT0, K0, 0, 0);
    pW[1] = loadW(WT0, K0, 0, 1);

    for (int k0 = 0; k0 < K0; k0 += 32) {
        #pragma unroll
        for (int i2 = 0; i2 < RT; i2++)
            *(int4*)(AsB + arow[i2] * 80 + aq * 16) = pA[i2];
        #pragma unroll
        for (int i2 = 0; i2 < 2; i2++) {
            const int flat = i2 * NTHR + tid;
            *(int4*)(WsB + (flat >> 2) * 80 + (flat & 3) * 16) = pW[i2];
        }
        __syncthreads();
        if (k0 + 32 < K0) {
            #pragma unroll
            for (int i2 = 0; i2 < RT; i2++) pA[i2] = loadA(k0 + 32, i2);
            pW[0] = loadW(WT0, K0, k0 + 32, 0);
            pW[1] = loadW(WT0, K0, k0 + 32, 1);
        }
        short8 a[RT];
        #pragma unroll
        for (int rt = 0; rt < RT; rt++) a[rt] = *(const short8*)(AsB + aoff[rt]);
        #pragma unroll
        for (int ct = 0; ct < 8; ct++) {
            const short8 b = *(const short8*)(WsB + boff + ct * 1280);
            #pragma unroll
            for (int rt = 0; rt < RT; rt++)
                acc[rt][ct] = __builtin_amdgcn_mfma_f32_16x16x32_bf16(a[rt], b, acc[rt][ct], 0, 0, 0);
        }
        __syncthreads();
    }
    {
        float bb[8];
        #pragma unroll
        for (int ct = 0; ct < 8; ct++) bb[ct] = ldmix(b0, poff + ct * 16 + m15, isf32);
        #pragma unroll
        for (int rt = 0; rt < RT; rt++)
            #pragma unroll
            for (int ct = 0; ct < 8; ct++)
                #pragma unroll
                for (int i = 0; i < 4; i++) {
                    const int rl = rt * 16 + quad * 4 + i;
                    const int col = ct * 16 + m15;
                    *(__hip_bfloat16*)(hw + rl * H_STRIDE + col * 2) =
                        __float2bfloat16(fmaxf(acc[rt][ct][i] + bb[ct], 0.f));
                }
    }

    // ===================== layer 1 =====================
    {
        #pragma unroll
        for (int rt = 0; rt < RT; rt++)
            #pragma unroll
            for (int ct = 0; ct < 8; ct++) acc[rt][ct] = (floatx4)0.f;
        short8 af[RT][4];
        #pragma unroll
        for (int rt = 0; rt < RT; rt++)
            #pragma unroll
            for (int c = 0; c < 4; c++)
                af[rt][c] = *(const short8*)(hw + (rt * 16 + m15) * H_STRIDE + c * 64 + quad * 16);
        int4 qW[2];
        qW[0] = loadW(WT1, L, 0, 0);
        qW[1] = loadW(WT1, L, 0, 1);
        for (int c = 0; c < 4; c++) {
            #pragma unroll
            for (int i2 = 0; i2 < 2; i2++) {
                const int flat = i2 * NTHR + tid;
                *(int4*)(WsB + (flat >> 2) * 80 + (flat & 3) * 16) = qW[i2];
            }
            __syncthreads();
            if (c < 3) {
                qW[0] = loadW(WT1, L, (c + 1) * 32, 0);
                qW[1] = loadW(WT1, L, (c + 1) * 32, 1);
            }
            #pragma unroll
            for (int ct = 0; ct < 8; ct++) {
                const short8 b = *(const short8*)(WsB + boff + ct * 1280);
                #pragma unroll
                for (int rt = 0; rt < RT; rt++)
                    acc[rt][ct] = __builtin_amdgcn_mfma_f32_16x16x32_bf16(af[rt][c], b, acc[rt][ct], 0, 0, 0);
            }
            __syncthreads();
        }
        float bb[8];
        #pragma unroll
        for (int ct = 0; ct < 8; ct++) bb[ct] = ldmix(b1, poff + ct * 16 + m15, isf32);
        #pragma unroll
        for (int rt = 0; rt < RT; rt++)
            #pragma unroll
            for (int ct = 0; ct < 8; ct++)
                #pragma unroll
                for (int i = 0; i < 4; i++) {
                    const int rl = rt * 16 + quad * 4 + i;
                    const int col = ct * 16 + m15;
                    *(__hip_bfloat16*)(hw + rl * H_STRIDE + col * 2) =
                        __float2bfloat16(fmaxf(acc[rt][ct][i] + bb[ct], 0.f));
                }
    }

    if constexpr (NL == 3) {
        // ===================== layer 2 + LN epilogue =====================
        #pragma unroll
        for (int rt = 0; rt < RT; rt++)
            #pragma unroll
            for (int ct = 0; ct < 8; ct++) acc[rt][ct] = (floatx4)0.f;
        short8 af[RT][4];
        #pragma unroll
        for (int rt = 0; rt < RT; rt++)
            #pragma unroll
            for (int c = 0; c < 4; c++)
                af[rt][c] = *(const short8*)(hw + (rt * 16 + m15) * H_STRIDE + c * 64 + quad * 16);
        int4 qW[2];
        qW[0] = loadW(WT2, L, 0, 0);
        qW[1] = loadW(WT2, L, 0, 1);
        for (int c = 0; c < 4; c++) {
            #pragma unroll
            for (int i2 = 0; i2 < 2; i2++) {
                const int flat = i2 * NTHR + tid;
                *(int4*)(WsB + (flat >> 2) * 80 + (flat & 3) * 16) = qW[i2];
            }
            __syncthreads();
            if (c < 3) {
                qW[0] = loadW(WT2, L, (c + 1) * 32, 0);
                qW[1] = loadW(WT2, L, (c + 1) * 32, 1);
            }
            #pragma unroll
            for (int ct = 0; ct < 8; ct++) {
                const short8 b = *(const short8*)(WsB + boff + ct * 1280);
                #pragma unroll
                for (int rt = 0; rt < RT; rt++)
                    acc[rt][ct] = __builtin_amdgcn_mfma_f32_16x16x32_bf16(af[rt][c], b, acc[rt][ct], 0, 0, 0);
            }
            __syncthreads();
        }
        float bb[8], gg[8], be[8];
        #pragma unroll
        for (int ct = 0; ct < 8; ct++) {
            bb[ct] = ldmix(b2,   poff + ct * 16 + m15, isf32);
            gg[ct] = ldmix(g,    poff + ct * 16 + m15, isf32);
            be[ct] = ldmix(beta, poff + ct * 16 + m15, isf32);
        }
        #pragma unroll
        for (int rt = 0; rt < RT; rt++) {
            #pragma unroll
            for (int i = 0; i < 4; i++) {
                float t[8], s = 0.f, s2 = 0.f;
                #pragma unroll
                for (int ct = 0; ct < 8; ct++) {
                    t[ct] = acc[rt][ct][i] + bb[ct];
                    s  += t[ct];
                    s2 += t[ct] * t[ct];
                }
                #pragma unroll
                for (int m = 1; m < 16; m <<= 1) {
                    s  += __shfl_xor(s,  m, 64);
                    s2 += __shfl_xor(s2, m, 64);
                }
                const float mean = s * (1.f / 128.f);
                const float var  = s2 * (1.f / 128.f) - mean * mean;
                const float inv  = rsqrtf(fmaxf(var, 0.f) + LN_EPS);
                const int rl = wv * 16 * RT + rt * 16 + quad * 4 + i;
                const int rg = row0 + rl;
                if (rg < M) {
                    #pragma unroll
                    for (int ct = 0; ct < 8; ct++) {
                        const int col = ct * 16 + m15;
                        const float o = (t[ct] - mean) * inv * gg[ct] + be[ct];
                        const size_t idx = (size_t)rg * L + col;
                        if constexpr (EPI == E_LN_STORE) {
                            res32[idx] = o;
                            if (res16) res16[idx] = __float2bfloat16(o);
                        } else if constexpr (EPI == E_LN_NODE) {
                            const float nw = res32[idx] + o;
                            res32[idx] = nw;
                            res16[idx] = __float2bfloat16(nw);
                        } else { // E_LN_EDGE
                            const float nw = res32[idx] + o;
                            res32[idx] = nw;
                            lnout[idx] = __float2bfloat16(o);
                        }
                    }
                }
            }
        }
    } else {
        // ===================== decoder head =====================
        __syncthreads();
        float* Wl = (float*)WsB;
        for (int i = tid; i < 3 * L; i += NTHR) {
            const int o = i / L, k = i - o * L;
            Wl[o * L + k] = ldmix(dW, k * 3 + o, isf32);
        }
        __syncthreads();
        if (tid < BMv) {
            const int rg = row0 + tid;
            if (rg < M) {
                const int wave = tid / (16 * RT);
                const int rw   = tid - wave * 16 * RT;
                const __hip_bfloat16* hr =
                    (const __hip_bfloat16*)(lds + wave * HW + rw * H_STRIDE);
                float s0 = ldmix(db, 0, isf32);
                float s1 = ldmix(db, 1, isf32);
                float s2 = ldmix(db, 2, isf32);
                #pragma unroll 8
                for (int k = 0; k < L; k++) {
                    const float hv = bf2f(hr[k]);
                    s0 += hv * Wl[k];
                    s1 += hv * Wl[L + k];
                    s2 += hv * Wl[2 * L + k];
                }
                if (isf32) {
                    float* o = (float*)dout;
                    o[rg * 3 + 0] = s0; o[rg * 3 + 1] = s1; o[rg * 3 + 2] = s2;
                } else {
                    __hip_bfloat16* o = (__hip_bfloat16*)dout;
                    o[rg * 3 + 0] = __float2bfloat16(s0);
                    o[rg * 3 + 1] = __float2bfloat16(s1);
                    o[rg * 3 + 2] = __float2bfloat16(s2);
                }
            }
        }
    }
}

// ---------------------------------------------------------------------------
extern "C" void kernel_launch(void* const* d_in, const int* in_sizes, int n_in,
                              void* d_out, int out_size, void* d_ws, size_t ws_size,
                              hipStream_t stream)
{
    (void)in_sizes; (void)n_in; (void)out_size; (void)ws_size;
    const int* snd = (const int*)d_in[2];
    const int* rcv = (const int*)d_in[3];

    char* ws = (char*)d_ws;
    int* cnt = (int*)ws;                              ws += 256;
    auto takeB = [&](size_t el) {
        __hip_bfloat16* p = (__hip_bfloat16*)ws;
        ws += ((el * 2 + 255) & ~255ull);
        return p;
    };
    auto takeF = [&](size_t el) {
        float* p = (float*)ws;
        ws += ((el * 4 + 255) & ~255ull);
        return p;
    };
    auto takeI = [&](size_t el) {
        int* p = (int*)ws;
        ws += ((el * 4 + 255) & ~255ull);
        return p;
    };

    const int srcIdx[N_TMATS] = {4, 6, 8, 12, 14, 16, 20, 22, 24, 28, 30, 32, 36, 38};
    const int tK[N_TMATS]    = {12, 128, 128, 7, 128, 128, 384, 128, 128, 256, 128, 128, 128, 128};
    const int tKp[N_TMATS]   = {32, 128, 128, 32, 128, 128, 384, 128, 128, 256, 128, 128, 128, 128};
    const int tNm[N_TMATS]   = {1, 1, 1, 1, 1, 1, STEPS, STEPS, STEPS, STEPS, STEPS, STEPS, 1, 1};
    TAll ta;
    long long cum = 0;
    __hip_bfloat16* wmat[N_TMATS];
    __hip_bfloat16* wpool = (__hip_bfloat16*)ws;
    for (int j = 0; j < N_TMATS; j++) {
        ta.src[j] = d_in[srcIdx[j]];
        ta.cum[j] = cum;
        ta.K[j] = tK[j]; ta.N[j] = 128; ta.Kpad[j] = tKp[j];
        wmat[j] = wpool + cum;
        cum += (long long)tNm[j] * 128 * tKp[j];
    }
    ta.cum[N_TMATS] = cum;
    ws += ((cum * 2 + 255) & ~255ull);

    float* n32 = takeF((size_t)N_NODES * L);
    float* e32 = takeF((size_t)N_EDGES * L);
    __hip_bfloat16* n16  = takeB((size_t)N_NODES * L);
    __hip_bfloat16* ln16 = takeB((size_t)N_EDGES * L);
    __hip_bfloat16* fN16 = takeB((size_t)N_NODES * 32);
    __hip_bfloat16* fE16 = takeB((size_t)N_EDGES * 32);
    int* deg    = takeI(N_NODES);
    int* rowptr = takeI(N_NODES + 1);
    int* cursor = takeI(N_NODES);
    int* elist  = takeI(N_EDGES);

    const dim3 blk(NTHR);
    const dim3 grdE((N_EDGES + 127) / 128);   // 625 (RT=2)
    const dim3 grdN((N_NODES + 63) / 64);     // 157 (RT=1)

    (void)hipMemsetAsync(cnt, 0, sizeof(int), stream);
    (void)hipMemsetAsync(deg, 0, N_NODES * sizeof(int), stream);
    detect_dtype<<<dim3(64), blk, 0, stream>>>((const uint32_t*)d_in[0], cnt);
    convert_feats<<<dim3(256), blk, 0, stream>>>(d_in[0], d_in[1], cnt, fN16, fE16);
    transpose_all<<<dim3(512), blk, 0, stream>>>(ta, cnt, wpool);

    csr_hist<<<dim3(80), blk, 0, stream>>>(rcv, deg);
    csr_scan<<<dim3(1), blk, 0, stream>>>(deg, rowptr, cursor);
    csr_scatter<<<dim3(80), blk, 0, stream>>>(rcv, cursor, elist);

    // ---- encoders ----
    fused_mlp<A_PLAIN, E_LN_STORE, 3, 2><<<grdE, blk, 0, stream>>>(
        fE16, 32, N_EDGES, 32, wmat[3], wmat[4], wmat[5],
        d_in[13], d_in[15], d_in[17], d_in[18], d_in[19], 0, cnt,
        nullptr, nullptr, nullptr, nullptr, nullptr, nullptr,
        e32, nullptr, nullptr, nullptr, nullptr, nullptr);
    fused_mlp<A_PLAIN, E_LN_STORE, 3, 1><<<grdN, blk, 0, stream>>>(
        fN16, 32, N_NODES, 32, wmat[0], wmat[1], wmat[2],
        d_in[5], d_in[7], d_in[9], d_in[10], d_in[11], 0, cnt,
        nullptr, nullptr, nullptr, nullptr, nullptr, nullptr,
        n32, n16, nullptr, nullptr, nullptr, nullptr);

    // ---- processor ----
    for (int s = 0; s < STEPS; s++) {
        const int po = s * L;
        fused_mlp<A_FEAT, E_LN_EDGE, 3, 2><<<grdE, blk, 0, stream>>>(
            nullptr, 0, N_EDGES, 384,
            wmat[6] + (size_t)s * 128 * 384,
            wmat[7] + (size_t)s * 128 * 128,
            wmat[8] + (size_t)s * 128 * 128,
            d_in[21], d_in[23], d_in[25], d_in[26], d_in[27], po, cnt,
            n16, nullptr, snd, rcv, nullptr, nullptr,
            e32, nullptr, ln16, nullptr, nullptr, nullptr);
        fused_mlp<A_CAT, E_LN_NODE, 3, 1><<<grdN, blk, 0, stream>>>(
            nullptr, 0, N_NODES, 256,
            wmat[9]  + (size_t)s * 128 * 256,
            wmat[10] + (size_t)s * 128 * 128,
            wmat[11] + (size_t)s * 128 * 128,
            d_in[29], d_in[31], d_in[33], d_in[34], d_in[35], po, cnt,
            n16, ln16, nullptr, nullptr, rowptr, elist,
            n32, n16, nullptr, nullptr, nullptr, nullptr);
    }

    // ---- decoder ----
    fused_mlp<A_PLAIN, E_DEC, 2, 1><<<grdN, blk, 0, stream>>>(
        n16, L, N_NODES, L, wmat[12], wmat[13], nullptr,
        d_in[37], d_in[39], nullptr, nullptr, nullptr, 0, cnt,
        nullptr, nullptr, nullptr, nullptr, nullptr, nullptr,
        nullptr, nullptr, nullptr, d_in[40], d_in[41], d_out);
}

// Round 7
// 1328.216 us; speedup vs baseline: 1.2398x; 1.2398x over previous
//
#include <hip/hip_runtime.h>
#include <hip/hip_bf16.h>
#include <stdint.h>

// ---------------------------------------------------------------------------
// EncodeProcessDecode (MeshGraphNets) on MI355X — Round 7:
//  * edge domain permuted to receiver-sorted order (one-time CSR sort);
//    all edge streams (fE16, e32, e16, ln16) stored sorted -> csr_agg is a
//    contiguous segmented sum, same summation order as r5 (numerics frozen)
//  * e16 bf16 residual stream restored (r6 regression reverted)
//  * edge kernel BM=64 grid=1250 (was grid-limited at 625), node grid 157
//
#define N_NODES 10000
#define N_EDGES 80000
#define L 128
#define STEPS 15
#define LN_EPS 1e-5f
#define NTHR 256
#define H_STRIDE 272

typedef short short8 __attribute__((ext_vector_type(8)));
typedef float floatx4 __attribute__((ext_vector_type(4)));

__device__ __forceinline__ float bf2f(const __hip_bfloat16 x) {
    return __bfloat162float(x);
}
__device__ __forceinline__ float ldmix(const void* p, int idx, int isf32) {
    return isf32 ? ((const float*)p)[idx]
                 : bf2f(((const __hip_bfloat16*)p)[idx]);
}

// ---------------------------------------------------------------------------
__global__ void detect_dtype(const uint32_t* __restrict__ nf, int* cnt) {
    int c = 0;
    for (int i = blockIdx.x * blockDim.x + threadIdx.x; i < 60000;
         i += gridDim.x * blockDim.x) {
        const uint32_t w = nf[i];
        c += (((w >> 7) & 0xFF) >= 0xC6) + (((w >> 23) & 0xFF) >= 0xC6);
    }
    atomicAdd(cnt, c);
}

// ---------------------------------------------------------------------------
#define N_TMATS 14
struct TAll {
    const void* src[N_TMATS];
    long long cum[N_TMATS + 1];
    int K[N_TMATS], N[N_TMATS], Kpad[N_TMATS];
};

__global__ void transpose_all(TAll a, const int* __restrict__ cnt,
                              __hip_bfloat16* __restrict__ pool) {
    const int isf32 = (*cnt > 1000);
    const long long total = a.cum[N_TMATS];
    for (long long i = blockIdx.x * (long long)blockDim.x + threadIdx.x;
         i < total; i += gridDim.x * (long long)blockDim.x) {
        int e = 0;
        #pragma unroll 1
        for (int j = 1; j < N_TMATS; j++) if (i >= a.cum[j]) e = j;
        const long long r = i - a.cum[e];
        const int per = a.N[e] * a.Kpad[e];
        const int m = (int)(r / per);
        const int r2 = (int)(r - (long long)m * per);
        const int nn = r2 / a.Kpad[e];
        const int kk = r2 - nn * a.Kpad[e];
        float v = 0.f;
        if (kk < a.K[e]) v = ldmix(a.src[e], (m * a.K[e] + kk) * a.N[e] + nn, isf32);
        pool[i] = __float2bfloat16(v);
    }
}

// fN plain; fE permuted to sorted-edge order via elist
__global__ void convert_feats(const void* __restrict__ nf,
                              const void* __restrict__ ef,
                              const int* __restrict__ cnt,
                              const int* __restrict__ elist,
                              __hip_bfloat16* __restrict__ fN,
                              __hip_bfloat16* __restrict__ fE)
{
    const int isf32 = (*cnt > 1000);
    const int totN = N_NODES * 32;
    const int totE = N_EDGES * 32;
    for (int i = blockIdx.x * blockDim.x + threadIdx.x; i < totN + totE;
         i += gridDim.x * blockDim.x) {
        if (i < totN) {
            const int r = i >> 5, c = i & 31;
            fN[i] = __float2bfloat16(c < 12 ? ldmix(nf, r * 12 + c, isf32) : 0.f);
        } else {
            const int j = i - totN;
            const int r = j >> 5, c = j & 31;
            const int e = elist[r];
            fE[j] = __float2bfloat16(c < 7 ? ldmix(ef, e * 7 + c, isf32) : 0.f);
        }
    }
}

// ---------------------------------------------------------------------------
// CSR build (receiver lists)
__global__ void csr_hist(const int* __restrict__ rcv, int* __restrict__ deg) {
    for (int i = blockIdx.x * blockDim.x + threadIdx.x; i < N_EDGES;
         i += gridDim.x * blockDim.x)
        atomicAdd(&deg[rcv[i]], 1);
}

__global__ void csr_scan(const int* __restrict__ deg, int* __restrict__ rowptr,
                         int* __restrict__ cursor) {
    __shared__ int part[256];
    __shared__ int partx[257];
    const int t = threadIdx.x;
    int s = 0;
    for (int j = 0; j < 40; j++) {
        const int i = t * 40 + j;
        if (i < N_NODES) s += deg[i];
    }
    part[t] = s;
    __syncthreads();
    if (t == 0) {
        int r = 0;
        for (int k = 0; k < 256; k++) { partx[k] = r; r += part[k]; }
        partx[256] = r;
    }
    __syncthreads();
    int run = partx[t];
    for (int j = 0; j < 40; j++) {
        const int i = t * 40 + j;
        if (i < N_NODES) {
            rowptr[i] = run;
            cursor[i] = run;
            run += deg[i];
        }
    }
    if (t == 255) rowptr[N_NODES] = partx[256];
}

__global__ void csr_scatter(const int* __restrict__ rcv, int* __restrict__ cursor,
                            int* __restrict__ elist) {
    for (int i = blockIdx.x * blockDim.x + threadIdx.x; i < N_EDGES;
         i += gridDim.x * blockDim.x) {
        const int p = atomicAdd(&cursor[rcv[i]], 1);
        elist[p] = i;
    }
}

// sorted-order sender/receiver index arrays
__global__ void sort_meta(const int* __restrict__ snd, const int* __restrict__ rcv,
                          const int* __restrict__ elist,
                          int* __restrict__ ssnd, int* __restrict__ srcv) {
    for (int i = blockIdx.x * blockDim.x + threadIdx.x; i < N_EDGES;
         i += gridDim.x * blockDim.x) {
        const int e = elist[i];
        ssnd[i] = snd[e];
        srcv[i] = rcv[e];
    }
}

// agg16[v] = bf16( sum over contiguous sorted rows [rowptr[v],rowptr[v+1]) )
__global__ __launch_bounds__(256)
void csr_agg(const int* __restrict__ rowptr,
             const __hip_bfloat16* __restrict__ ln16,
             __hip_bfloat16* __restrict__ agg16)
{
    const int g = threadIdx.x >> 5;
    const int lane = threadIdx.x & 31;
    const int v = blockIdx.x * 8 + g;
    if (v >= N_NODES) return;
    const int c0 = lane * 4;
    float s0 = 0.f, s1 = 0.f, s2 = 0.f, s3 = 0.f;
    int j = rowptr[v];
    const int en = rowptr[v + 1];
    for (; j + 1 < en; j += 2) {
        union { uint2 w; __hip_bfloat16 h[4]; } u0, u1;
        u0.w = *(const uint2*)(ln16 + (size_t)j * L + c0);
        u1.w = *(const uint2*)(ln16 + (size_t)(j + 1) * L + c0);
        s0 += bf2f(u0.h[0]); s1 += bf2f(u0.h[1]); s2 += bf2f(u0.h[2]); s3 += bf2f(u0.h[3]);
        s0 += bf2f(u1.h[0]); s1 += bf2f(u1.h[1]); s2 += bf2f(u1.h[2]); s3 += bf2f(u1.h[3]);
    }
    for (; j < en; j++) {
        union { uint2 w; __hip_bfloat16 h[4]; } u;
        u.w = *(const uint2*)(ln16 + (size_t)j * L + c0);
        s0 += bf2f(u.h[0]); s1 += bf2f(u.h[1]); s2 += bf2f(u.h[2]); s3 += bf2f(u.h[3]);
    }
    union { uint2 w; __hip_bfloat16 h[4]; } o;
    o.h[0] = __float2bfloat16(s0); o.h[1] = __float2bfloat16(s1);
    o.h[2] = __float2bfloat16(s2); o.h[3] = __float2bfloat16(s3);
    *(uint2*)(agg16 + (size_t)v * L + c0) = o.w;
}

// ---------------------------------------------------------------------------
enum AMode { A_PLAIN = 0, A_FEAT = 1, A_CAT = 2 };
enum Epi   { E_LN_STORE = 0, E_LN_EDGE = 1, E_LN_NODE = 2, E_DEC = 3 };

// Fused NL-layer MLP. Block: BMv = 64*RT rows x 128 cols, 4 waves.
template <int AMODE, int EPI, int NL, int RT, int MINW>
__global__ __launch_bounds__(NTHR, MINW)
void fused_mlp(const __hip_bfloat16* __restrict__ A, int lda, int M, int K0,
               const __hip_bfloat16* __restrict__ WT0,
               const __hip_bfloat16* __restrict__ WT1,
               const __hip_bfloat16* __restrict__ WT2,
               const void* __restrict__ b0,
               const void* __restrict__ b1,
               const void* __restrict__ b2,
               const void* __restrict__ g,
               const void* __restrict__ beta,
               int poff,
               const int* __restrict__ cnt,
               const __hip_bfloat16* __restrict__ n16,   // A_FEAT gathers / A_CAT reg0
               const __hip_bfloat16* __restrict__ e16s,  // A_FEAT reg2 (sorted)
               const __hip_bfloat16* __restrict__ agg16, // A_CAT reg1
               const int* __restrict__ ssnd,
               const int* __restrict__ srcv,
               float* res32,
               __hip_bfloat16* res16,
               __hip_bfloat16* __restrict__ lnout,
               const void* __restrict__ dW,
               const void* __restrict__ db,
               void* __restrict__ dout)
{
    constexpr int BMv   = 64 * RT;
    constexpr int HW    = RT * 16 * H_STRIDE;
    constexpr int WSOFF = 4 * HW;
    __shared__ __align__(16) char lds[WSOFF + 10240];
    char* AsB = lds;
    char* WsB = lds + WSOFF;

    const int tid  = threadIdx.x;
    const int wv   = tid >> 6;
    const int lane = tid & 63;
    const int quad = lane >> 4;
    const int m15  = lane & 15;
    const int row0 = blockIdx.x * BMv;
    const int isf32 = (*cnt > 1000);

    char* hw = lds + wv * HW;

    const int boff = m15 * 80 + quad * 16;
    int aoff[RT];
    #pragma unroll
    for (int rt = 0; rt < RT; rt++)
        aoff[rt] = (wv * 16 * RT + rt * 16 + m15) * 80 + quad * 16;

    const int aq = tid & 3;
    int arow[RT], sidx[RT], ridx[RT];
    #pragma unroll
    for (int i2 = 0; i2 < RT; i2++) {
        arow[i2] = (i2 * NTHR + tid) >> 2;
        if constexpr (AMODE == A_FEAT) {
            const int rg = row0 + arow[i2];
            sidx[i2] = (rg < M) ? ssnd[rg] : 0;
            ridx[i2] = (rg < M) ? srcv[rg] : 0;
        }
    }

    auto loadA = [&](int k0, int i2) -> int4 {
        const int rg = row0 + arow[i2];
        int4 av = make_int4(0, 0, 0, 0);
        if (rg < M) {
            if constexpr (AMODE == A_PLAIN) {
                av = *(const int4*)(A + (size_t)rg * lda + k0 + aq * 8);
            } else if constexpr (AMODE == A_FEAT) {
                const __hip_bfloat16* sp;
                if (k0 < 2 * L) {
                    const int nd = (k0 < L) ? sidx[i2] : ridx[i2];
                    sp = n16 + (size_t)nd * L + (k0 & (L - 1)) + aq * 8;
                } else {
                    sp = e16s + (size_t)rg * L + (k0 - 2 * L) + aq * 8;
                }
                av = *(const int4*)sp;
            } else { // A_CAT
                const __hip_bfloat16* sp = (k0 < L)
                    ? n16   + (size_t)rg * L + k0 + aq * 8
                    : agg16 + (size_t)rg * L + (k0 - L) + aq * 8;
                av = *(const int4*)sp;
            }
        }
        return av;
    };
    auto loadW = [&](const __hip_bfloat16* WT, int ksz, int k0, int i2) -> int4 {
        const int flat = i2 * NTHR + tid;
        return *(const int4*)(WT + (size_t)(flat >> 2) * ksz + k0 + (flat & 3) * 8);
    };

    floatx4 acc[RT][8];

    // ===================== layer 0 (reg-prefetch) =====================
    #pragma unroll
    for (int rt = 0; rt < RT; rt++)
        #pragma unroll
        for (int ct = 0; ct < 8; ct++) acc[rt][ct] = (floatx4)0.f;

    int4 pA[RT], pW[2];
    #pragma unroll
    for (int i2 = 0; i2 < RT; i2++) pA[i2] = loadA(0, i2);
    pW[0] = loadW(WT0, K0, 0, 0);
    pW[1] = loadW(WT0, K0, 0, 1);

    for (int k0 = 0; k0 < K0; k0 += 32) {
        #pragma unroll
        for (int i2 = 0; i2 < RT; i2++)
            *(int4*)(AsB + arow[i2] * 80 + aq * 16) = pA[i2];
        #pragma unroll
        for (int i2 = 0; i2 < 2; i2++) {
            const int flat = i2 * NTHR + tid;
            *(int4*)(WsB + (flat >> 2) * 80 + (flat & 3) * 16) = pW[i2];
        }
        __syncthreads();
        if (k0 + 32 < K0) {
            #pragma unroll
            for (int i2 = 0; i2 < RT; i2++) pA[i2] = loadA(k0 + 32, i2);
            pW[0] = loadW(WT0, K0, k0 + 32, 0);
            pW[1] = loadW(WT0, K0, k0 + 32, 1);
        }
        short8 a[RT];
        #pragma unroll
        for (int rt = 0; rt < RT; rt++) a[rt] = *(const short8*)(AsB + aoff[rt]);
        #pragma unroll
        for (int ct = 0; ct < 8; ct++) {
            const short8 b = *(const short8*)(WsB + boff + ct * 1280);
            #pragma unroll
            for (int rt = 0; rt < RT; rt++)
                acc[rt][ct] = __builtin_amdgcn_mfma_f32_16x16x32_bf16(a[rt], b, acc[rt][ct], 0, 0, 0);
        }
        __syncthreads();
    }
    {
        float bb[8];
        #pragma unroll
        for (int ct = 0; ct < 8; ct++) bb[ct] = ldmix(b0, poff + ct * 16 + m15, isf32);
        #pragma unroll
        for (int rt = 0; rt < RT; rt++)
            #pragma unroll
            for (int ct = 0; ct < 8; ct++)
                #pragma unroll
                for (int i = 0; i < 4; i++) {
                    const int rl = rt * 16 + quad * 4 + i;
                    const int col = ct * 16 + m15;
                    *(__hip_bfloat16*)(hw + rl * H_STRIDE + col * 2) =
                        __float2bfloat16(fmaxf(acc[rt][ct][i] + bb[ct], 0.f));
                }
    }

    // ===================== layer 1 =====================
    {
        #pragma unroll
        for (int rt = 0; rt < RT; rt++)
            #pragma unroll
            for (int ct = 0; ct < 8; ct++) acc[rt][ct] = (floatx4)0.f;
        short8 af[RT][4];
        #pragma unroll
        for (int rt = 0; rt < RT; rt++)
            #pragma unroll
            for (int c = 0; c < 4; c++)
                af[rt][c] = *(const short8*)(hw + (rt * 16 + m15) * H_STRIDE + c * 64 + quad * 16);
        int4 qW[2];
        qW[0] = loadW(WT1, L, 0, 0);
        qW[1] = loadW(WT1, L, 0, 1);
        for (int c = 0; c < 4; c++) {
            #pragma unroll
            for (int i2 = 0; i2 < 2; i2++) {
                const int flat = i2 * NTHR + tid;
                *(int4*)(WsB + (flat >> 2) * 80 + (flat & 3) * 16) = qW[i2];
            }
            __syncthreads();
            if (c < 3) {
                qW[0] = loadW(WT1, L, (c + 1) * 32, 0);
                qW[1] = loadW(WT1, L, (c + 1) * 32, 1);
            }
            #pragma unroll
            for (int ct = 0; ct < 8; ct++) {
                const short8 b = *(const short8*)(WsB + boff + ct * 1280);
                #pragma unroll
                for (int rt = 0; rt < RT; rt++)
                    acc[rt][ct] = __builtin_amdgcn_mfma_f32_16x16x32_bf16(af[rt][c], b, acc[rt][ct], 0, 0, 0);
            }
            __syncthreads();
        }
        float bb[8];
        #pragma unroll
        for (int ct = 0; ct < 8; ct++) bb[ct] = ldmix(b1, poff + ct * 16 + m15, isf32);
        #pragma unroll
        for (int rt = 0; rt < RT; rt++)
            #pragma unroll
            for (int ct = 0; ct < 8; ct++)
                #pragma unroll
                for (int i = 0; i < 4; i++) {
                    const int rl = rt * 16 + quad * 4 + i;
                    const int col = ct * 16 + m15;
                    *(__hip_bfloat16*)(hw + rl * H_STRIDE + col * 2) =
                        __float2bfloat16(fmaxf(acc[rt][ct][i] + bb[ct], 0.f));
                }
    }

    if constexpr (NL == 3) {
        // ===================== layer 2 + LN epilogue =====================
        #pragma unroll
        for (int rt = 0; rt < RT; rt++)
            #pragma unroll
            for (int ct = 0; ct < 8; ct++) acc[rt][ct] = (floatx4)0.f;
        short8 af[RT][4];
        #pragma unroll
        for (int rt = 0; rt < RT; rt++)
            #pragma unroll
            for (int c = 0; c < 4; c++)
                af[rt][c] = *(const short8*)(hw + (rt * 16 + m15) * H_STRIDE + c * 64 + quad * 16);
        int4 qW[2];
        qW[0] = loadW(WT2, L, 0, 0);
        qW[1] = loadW(WT2, L, 0, 1);
        for (int c = 0; c < 4; c++) {
            #pragma unroll
            for (int i2 = 0; i2 < 2; i2++) {
                const int flat = i2 * NTHR + tid;
                *(int4*)(WsB + (flat >> 2) * 80 + (flat & 3) * 16) = qW[i2];
            }
            __syncthreads();
            if (c < 3) {
                qW[0] = loadW(WT2, L, (c + 1) * 32, 0);
                qW[1] = loadW(WT2, L, (c + 1) * 32, 1);
            }
            #pragma unroll
            for (int ct = 0; ct < 8; ct++) {
                const short8 b = *(const short8*)(WsB + boff + ct * 1280);
                #pragma unroll
                for (int rt = 0; rt < RT; rt++)
                    acc[rt][ct] = __builtin_amdgcn_mfma_f32_16x16x32_bf16(af[rt][c], b, acc[rt][ct], 0, 0, 0);
            }
            __syncthreads();
        }
        float bb[8], gg[8], be[8];
        #pragma unroll
        for (int ct = 0; ct < 8; ct++) {
            bb[ct] = ldmix(b2,   poff + ct * 16 + m15, isf32);
            gg[ct] = ldmix(g,    poff + ct * 16 + m15, isf32);
            be[ct] = ldmix(beta, poff + ct * 16 + m15, isf32);
        }
        #pragma unroll
        for (int rt = 0; rt < RT; rt++) {
            #pragma unroll
            for (int i = 0; i < 4; i++) {
                float t[8], s = 0.f, s2 = 0.f;
                #pragma unroll
                for (int ct = 0; ct < 8; ct++) {
                    t[ct] = acc[rt][ct][i] + bb[ct];
                    s  += t[ct];
                    s2 += t[ct] * t[ct];
                }
                #pragma unroll
                for (int m = 1; m < 16; m <<= 1) {
                    s  += __shfl_xor(s,  m, 64);
                    s2 += __shfl_xor(s2, m, 64);
                }
                const float mean = s * (1.f / 128.f);
                const float var  = s2 * (1.f / 128.f) - mean * mean;
                const float inv  = rsqrtf(fmaxf(var, 0.f) + LN_EPS);
                const int rl = wv * 16 * RT + rt * 16 + quad * 4 + i;
                const int rg = row0 + rl;
                if (rg < M) {
                    #pragma unroll
                    for (int ct = 0; ct < 8; ct++) {
                        const int col = ct * 16 + m15;
                        const float o = (t[ct] - mean) * inv * gg[ct] + be[ct];
                        const size_t idx = (size_t)rg * L + col;
                        if constexpr (EPI == E_LN_STORE) {
                            res32[idx] = o;
                            if (res16) res16[idx] = __float2bfloat16(o);
                        } else if constexpr (EPI == E_LN_NODE) {
                            const float nw = res32[idx] + o;
                            res32[idx] = nw;
                            res16[idx] = __float2bfloat16(nw);
                        } else { // E_LN_EDGE
                            const float nw = res32[idx] + o;
                            res32[idx] = nw;
                            res16[idx] = __float2bfloat16(nw);
                            lnout[idx] = __float2bfloat16(o);
                        }
                    }
                }
            }
        }
    } else {
        // ===================== decoder head =====================
        __syncthreads();
        float* Wl = (float*)WsB;
        for (int i = tid; i < 3 * L; i += NTHR) {
            const int o = i / L, k = i - o * L;
            Wl[o * L + k] = ldmix(dW, k * 3 + o, isf32);
        }
        __syncthreads();
        if (tid < BMv) {
            const int rg = row0 + tid;
            if (rg < M) {
                const int wave = tid / (16 * RT);
                const int rw   = tid - wave * 16 * RT;
                const __hip_bfloat16* hr =
                    (const __hip_bfloat16*)(lds + wave * HW + rw * H_STRIDE);
                float s0 = ldmix(db, 0, isf32);
                float s1 = ldmix(db, 1, isf32);
                float s2 = ldmix(db, 2, isf32);
                #pragma unroll 8
                for (int k = 0; k < L; k++) {
                    const float hv = bf2f(hr[k]);
                    s0 += hv * Wl[k];
                    s1 += hv * Wl[L + k];
                    s2 += hv * Wl[2 * L + k];
                }
                if (isf32) {
                    float* o = (float*)dout;
                    o[rg * 3 + 0] = s0; o[rg * 3 + 1] = s1; o[rg * 3 + 2] = s2;
                } else {
                    __hip_bfloat16* o = (__hip_bfloat16*)dout;
                    o[rg * 3 + 0] = __float2bfloat16(s0);
                    o[rg * 3 + 1] = __float2bfloat16(s1);
                    o[rg * 3 + 2] = __float2bfloat16(s2);
                }
            }
        }
    }
}

// ---------------------------------------------------------------------------
extern "C" void kernel_launch(void* const* d_in, const int* in_sizes, int n_in,
                              void* d_out, int out_size, void* d_ws, size_t ws_size,
                              hipStream_t stream)
{
    (void)in_sizes; (void)n_in; (void)out_size; (void)ws_size;
    const int* snd = (const int*)d_in[2];
    const int* rcv = (const int*)d_in[3];

    char* ws = (char*)d_ws;
    int* cnt = (int*)ws;                              ws += 256;
    auto takeB = [&](size_t el) {
        __hip_bfloat16* p = (__hip_bfloat16*)ws;
        ws += ((el * 2 + 255) & ~255ull);
        return p;
    };
    auto takeF = [&](size_t el) {
        float* p = (float*)ws;
        ws += ((el * 4 + 255) & ~255ull);
        return p;
    };
    auto takeI = [&](size_t el) {
        int* p = (int*)ws;
        ws += ((el * 4 + 255) & ~255ull);
        return p;
    };

    const int srcIdx[N_TMATS] = {4, 6, 8, 12, 14, 16, 20, 22, 24, 28, 30, 32, 36, 38};
    const int tK[N_TMATS]    = {12, 128, 128, 7, 128, 128, 384, 128, 128, 256, 128, 128, 128, 128};
    const int tKp[N_TMATS]   = {32, 128, 128, 32, 128, 128, 384, 128, 128, 256, 128, 128, 128, 128};
    const int tNm[N_TMATS]   = {1, 1, 1, 1, 1, 1, STEPS, STEPS, STEPS, STEPS, STEPS, STEPS, 1, 1};
    TAll ta;
    long long cum = 0;
    __hip_bfloat16* wmat[N_TMATS];
    __hip_bfloat16* wpool = (__hip_bfloat16*)ws;
    for (int j = 0; j < N_TMATS; j++) {
        ta.src[j] = d_in[srcIdx[j]];
        ta.cum[j] = cum;
        ta.K[j] = tK[j]; ta.N[j] = 128; ta.Kpad[j] = tKp[j];
        wmat[j] = wpool + cum;
        cum += (long long)tNm[j] * 128 * tKp[j];
    }
    ta.cum[N_TMATS] = cum;
    ws += ((cum * 2 + 255) & ~255ull);

    float* n32 = takeF((size_t)N_NODES * L);
    float* e32 = takeF((size_t)N_EDGES * L);
    __hip_bfloat16* n16   = takeB((size_t)N_NODES * L);
    __hip_bfloat16* e16   = takeB((size_t)N_EDGES * L);
    __hip_bfloat16* ln16  = takeB((size_t)N_EDGES * L);
    __hip_bfloat16* agg16 = takeB((size_t)N_NODES * L);
    __hip_bfloat16* fN16  = takeB((size_t)N_NODES * 32);
    __hip_bfloat16* fE16  = takeB((size_t)N_EDGES * 32);
    int* deg    = takeI(N_NODES);
    int* rowptr = takeI(N_NODES + 1);
    int* cursor = takeI(N_NODES);
    int* elist  = takeI(N_EDGES);
    int* ssnd   = takeI(N_EDGES);
    int* srcv   = takeI(N_EDGES);

    const dim3 blk(NTHR);
    const dim3 grdE((N_EDGES + 63) / 64);     // 1250 (RT=1)
    const dim3 grdN((N_NODES + 63) / 64);     // 157  (RT=1)

    (void)hipMemsetAsync(cnt, 0, sizeof(int), stream);
    (void)hipMemsetAsync(deg, 0, N_NODES * sizeof(int), stream);
    detect_dtype<<<dim3(64), blk, 0, stream>>>((const uint32_t*)d_in[0], cnt);
    transpose_all<<<dim3(512), blk, 0, stream>>>(ta, cnt, wpool);

    csr_hist<<<dim3(80), blk, 0, stream>>>(rcv, deg);
    csr_scan<<<dim3(1), blk, 0, stream>>>(deg, rowptr, cursor);
    csr_scatter<<<dim3(80), blk, 0, stream>>>(rcv, cursor, elist);
    sort_meta<<<dim3(80), blk, 0, stream>>>(snd, rcv, elist, ssnd, srcv);
    convert_feats<<<dim3(256), blk, 0, stream>>>(d_in[0], d_in[1], cnt, elist, fN16, fE16);

    // ---- encoders (edge streams in sorted order) ----
    fused_mlp<A_PLAIN, E_LN_STORE, 3, 1, 3><<<grdE, blk, 0, stream>>>(
        fE16, 32, N_EDGES, 32, wmat[3], wmat[4], wmat[5],
        d_in[13], d_in[15], d_in[17], d_in[18], d_in[19], 0, cnt,
        nullptr, nullptr, nullptr, nullptr, nullptr,
        e32, e16, nullptr, nullptr, nullptr, nullptr);
    fused_mlp<A_PLAIN, E_LN_STORE, 3, 1, 3><<<grdN, blk, 0, stream>>>(
        fN16, 32, N_NODES, 32, wmat[0], wmat[1], wmat[2],
        d_in[5], d_in[7], d_in[9], d_in[10], d_in[11], 0, cnt,
        nullptr, nullptr, nullptr, nullptr, nullptr,
        n32, n16, nullptr, nullptr, nullptr, nullptr);

    // ---- processor ----
    for (int s = 0; s < STEPS; s++) {
        const int po = s * L;
        fused_mlp<A_FEAT, E_LN_EDGE, 3, 1, 3><<<grdE, blk, 0, stream>>>(
            nullptr, 0, N_EDGES, 384,
            wmat[6] + (size_t)s * 128 * 384,
            wmat[7] + (size_t)s * 128 * 128,
            wmat[8] + (size_t)s * 128 * 128,
            d_in[21], d_in[23], d_in[25], d_in[26], d_in[27], po, cnt,
            n16, e16, nullptr, ssnd, srcv,
            e32, e16, ln16, nullptr, nullptr, nullptr);
        csr_agg<<<dim3((N_NODES + 7) / 8), blk, 0, stream>>>(rowptr, ln16, agg16);
        fused_mlp<A_CAT, E_LN_NODE, 3, 1, 3><<<grdN, blk, 0, stream>>>(
            nullptr, 0, N_NODES, 256,
            wmat[9]  + (size_t)s * 128 * 256,
            wmat[10] + (size_t)s * 128 * 128,
            wmat[11] + (size_t)s * 128 * 128,
            d_in[29], d_in[31], d_in[33], d_in[34], d_in[35], po, cnt,
            n16, nullptr, agg16, nullptr, nullptr,
            n32, n16, nullptr, nullptr, nullptr, nullptr);
    }

    // ---- decoder ----
    fused_mlp<A_PLAIN, E_DEC, 2, 1, 3><<<grdN, blk, 0, stream>>>(
        n16, L, N_NODES, L, wmat[12], wmat[13], nullptr,
        d_in[37], d_in[39], nullptr, nullptr, nullptr, 0, cnt,
        nullptr, nullptr, nullptr, nullptr, nullptr,
        nullptr, nullptr, nullptr, d_in[40], d_in[41], d_out);
}

// Round 8
// 1321.557 us; speedup vs baseline: 1.2460x; 1.0050x over previous
//
#include <hip/hip_runtime.h>
#include <hip/hip_bf16.h>
#include <stdint.h>

// ---------------------------------------------------------------------------
// EncodeProcessDecode (MeshGraphNets) on MI355X — Round 8:
//  * A-fragments loaded directly global->registers (no A LDS staging/barriers)
//  * W pre-shuffled to B-fragment order; 64-k sections double-buffered in LDS,
//    ONE barrier per section (was 2 per 32-k chunk)
//  * W/A for section s+1 prefetched during section s compute
//  Numerics bit-identical to round 7 (absmax 0.0703125).
//
#define N_NODES 10000
#define N_EDGES 80000
#define L 128
#define STEPS 15
#define LN_EPS 1e-5f
#define NTHR 256
#define H_STRIDE 272

typedef short short8 __attribute__((ext_vector_type(8)));
typedef float floatx4 __attribute__((ext_vector_type(4)));

__device__ __forceinline__ float bf2f(const __hip_bfloat16 x) {
    return __bfloat162float(x);
}
__device__ __forceinline__ float ldmix(const void* p, int idx, int isf32) {
    return isf32 ? ((const float*)p)[idx]
                 : bf2f(((const __hip_bfloat16*)p)[idx]);
}

// ---------------------------------------------------------------------------
__global__ void detect_dtype(const uint32_t* __restrict__ nf, int* cnt) {
    int c = 0;
    for (int i = blockIdx.x * blockDim.x + threadIdx.x; i < 60000;
         i += gridDim.x * blockDim.x) {
        const uint32_t w = nf[i];
        c += (((w >> 7) & 0xFF) >= 0xC6) + (((w >> 23) & 0xFF) >= 0xC6);
    }
    atomicAdd(cnt, c);
}

// ---------------------------------------------------------------------------
// Weights -> bf16 in B-fragment order:
// per 32-k chunk c2: [ct(8)][lane(64)][j(8)] where
//   k = c2*32 + (lane>>4)*8 + j, col = ct*16 + (lane&15)
#define N_TMATS 14
struct TAll {
    const void* src[N_TMATS];
    long long cum[N_TMATS + 1];
    int K[N_TMATS], N[N_TMATS], Kpad[N_TMATS];
};

__global__ void transpose_all(TAll a, const int* __restrict__ cnt,
                              __hip_bfloat16* __restrict__ pool) {
    const int isf32 = (*cnt > 1000);
    const long long total = a.cum[N_TMATS];
    for (long long i = blockIdx.x * (long long)blockDim.x + threadIdx.x;
         i < total; i += gridDim.x * (long long)blockDim.x) {
        int e = 0;
        #pragma unroll 1
        for (int j = 1; j < N_TMATS; j++) if (i >= a.cum[j]) e = j;
        const long long r = i - a.cum[e];
        const int per = a.N[e] * a.Kpad[e];
        const int m = (int)(r / per);
        int r2 = (int)(r - (long long)m * per);
        const int c2   = r2 >> 12;           // /4096
        const int rem  = r2 & 4095;
        const int ct   = rem >> 9;
        const int lane = (rem >> 3) & 63;
        const int j    = rem & 7;
        const int k    = c2 * 32 + (lane >> 4) * 8 + j;
        const int col  = ct * 16 + (lane & 15);
        float v = 0.f;
        if (k < a.K[e]) v = ldmix(a.src[e], (m * a.K[e] + k) * a.N[e] + col, isf32);
        pool[i] = __float2bfloat16(v);
    }
}

// fN plain; fE permuted to sorted-edge order via elist
__global__ void convert_feats(const void* __restrict__ nf,
                              const void* __restrict__ ef,
                              const int* __restrict__ cnt,
                              const int* __restrict__ elist,
                              __hip_bfloat16* __restrict__ fN,
                              __hip_bfloat16* __restrict__ fE)
{
    const int isf32 = (*cnt > 1000);
    const int totN = N_NODES * 32;
    const int totE = N_EDGES * 32;
    for (int i = blockIdx.x * blockDim.x + threadIdx.x; i < totN + totE;
         i += gridDim.x * blockDim.x) {
        if (i < totN) {
            const int r = i >> 5, c = i & 31;
            fN[i] = __float2bfloat16(c < 12 ? ldmix(nf, r * 12 + c, isf32) : 0.f);
        } else {
            const int j = i - totN;
            const int r = j >> 5, c = j & 31;
            const int e = elist[r];
            fE[j] = __float2bfloat16(c < 7 ? ldmix(ef, e * 7 + c, isf32) : 0.f);
        }
    }
}

// ---------------------------------------------------------------------------
// CSR build (receiver lists)
__global__ void csr_hist(const int* __restrict__ rcv, int* __restrict__ deg) {
    for (int i = blockIdx.x * blockDim.x + threadIdx.x; i < N_EDGES;
         i += gridDim.x * blockDim.x)
        atomicAdd(&deg[rcv[i]], 1);
}

__global__ void csr_scan(const int* __restrict__ deg, int* __restrict__ rowptr,
                         int* __restrict__ cursor) {
    __shared__ int part[256];
    __shared__ int partx[257];
    const int t = threadIdx.x;
    int s = 0;
    for (int j = 0; j < 40; j++) {
        const int i = t * 40 + j;
        if (i < N_NODES) s += deg[i];
    }
    part[t] = s;
    __syncthreads();
    if (t == 0) {
        int r = 0;
        for (int k = 0; k < 256; k++) { partx[k] = r; r += part[k]; }
        partx[256] = r;
    }
    __syncthreads();
    int run = partx[t];
    for (int j = 0; j < 40; j++) {
        const int i = t * 40 + j;
        if (i < N_NODES) {
            rowptr[i] = run;
            cursor[i] = run;
            run += deg[i];
        }
    }
    if (t == 255) rowptr[N_NODES] = partx[256];
}

__global__ void csr_scatter(const int* __restrict__ rcv, int* __restrict__ cursor,
                            int* __restrict__ elist) {
    for (int i = blockIdx.x * blockDim.x + threadIdx.x; i < N_EDGES;
         i += gridDim.x * blockDim.x) {
        const int p = atomicAdd(&cursor[rcv[i]], 1);
        elist[p] = i;
    }
}

__global__ void sort_meta(const int* __restrict__ snd, const int* __restrict__ rcv,
                          const int* __restrict__ elist,
                          int* __restrict__ ssnd, int* __restrict__ srcv) {
    for (int i = blockIdx.x * blockDim.x + threadIdx.x; i < N_EDGES;
         i += gridDim.x * blockDim.x) {
        const int e = elist[i];
        ssnd[i] = snd[e];
        srcv[i] = rcv[e];
    }
}

// agg16[v] = bf16( sum over contiguous sorted rows [rowptr[v],rowptr[v+1]) )
__global__ __launch_bounds__(256)
void csr_agg(const int* __restrict__ rowptr,
             const __hip_bfloat16* __restrict__ ln16,
             __hip_bfloat16* __restrict__ agg16)
{
    const int g = threadIdx.x >> 5;
    const int lane = threadIdx.x & 31;
    const int v = blockIdx.x * 8 + g;
    if (v >= N_NODES) return;
    const int c0 = lane * 4;
    float s0 = 0.f, s1 = 0.f, s2 = 0.f, s3 = 0.f;
    int j = rowptr[v];
    const int en = rowptr[v + 1];
    for (; j + 1 < en; j += 2) {
        union { uint2 w; __hip_bfloat16 h[4]; } u0, u1;
        u0.w = *(const uint2*)(ln16 + (size_t)j * L + c0);
        u1.w = *(const uint2*)(ln16 + (size_t)(j + 1) * L + c0);
        s0 += bf2f(u0.h[0]); s1 += bf2f(u0.h[1]); s2 += bf2f(u0.h[2]); s3 += bf2f(u0.h[3]);
        s0 += bf2f(u1.h[0]); s1 += bf2f(u1.h[1]); s2 += bf2f(u1.h[2]); s3 += bf2f(u1.h[3]);
    }
    for (; j < en; j++) {
        union { uint2 w; __hip_bfloat16 h[4]; } u;
        u.w = *(const uint2*)(ln16 + (size_t)j * L + c0);
        s0 += bf2f(u.h[0]); s1 += bf2f(u.h[1]); s2 += bf2f(u.h[2]); s3 += bf2f(u.h[3]);
    }
    union { uint2 w; __hip_bfloat16 h[4]; } o;
    o.h[0] = __float2bfloat16(s0); o.h[1] = __float2bfloat16(s1);
    o.h[2] = __float2bfloat16(s2); o.h[3] = __float2bfloat16(s3);
    *(uint2*)(agg16 + (size_t)v * L + c0) = o.w;
}

// ---------------------------------------------------------------------------
enum AMode { A_PLAIN = 0, A_FEAT = 1, A_CAT = 2 };
enum Epi   { E_LN_STORE = 0, E_LN_EDGE = 1, E_LN_NODE = 2, E_DEC = 3 };

// Fused NL-layer MLP. Block: 64 rows x 128 cols, 4 waves; wave w owns rows
// [w*16, w*16+16). A-frags direct global->reg; W double-buffered in LDS,
// 1 barrier per 64-k section.
template <int AMODE, int EPI, int NL, int K0>
__global__ __launch_bounds__(NTHR, 3)
void fused_mlp(const __hip_bfloat16* __restrict__ A, int lda, int M,
               const __hip_bfloat16* __restrict__ WT0,
               const __hip_bfloat16* __restrict__ WT1,
               const __hip_bfloat16* __restrict__ WT2,
               const void* __restrict__ b0,
               const void* __restrict__ b1,
               const void* __restrict__ b2,
               const void* __restrict__ g,
               const void* __restrict__ beta,
               int poff,
               const int* __restrict__ cnt,
               const __hip_bfloat16* __restrict__ n16,
               const __hip_bfloat16* __restrict__ e16s,
               const __hip_bfloat16* __restrict__ agg16,
               const int* __restrict__ ssnd,
               const int* __restrict__ srcv,
               float* res32,
               __hip_bfloat16* res16,
               __hip_bfloat16* __restrict__ lnout,
               const void* __restrict__ dW,
               const void* __restrict__ db,
               void* __restrict__ dout)
{
    __shared__ __align__(16) char lds[17408 + 32768];
    char* wbuf = lds + 17408;

    const int tid  = threadIdx.x;
    const int wv   = tid >> 6;
    const int lane = tid & 63;
    const int quad = lane >> 4;
    const int m15  = lane & 15;
    const int row0 = blockIdx.x * 64;
    const int isf32 = (*cnt > 1000);

    char* hw = lds + wv * 4352;    // this wave's 16x128 activation buffer

    const int rw = row0 + wv * 16 + m15;      // this lane's output row
    const int rc = rw < M ? rw : M - 1;       // clamped for loads

    int sI = 0, rI = 0;
    if constexpr (AMODE == A_FEAT) { sI = ssnd[rc]; rI = srcv[rc]; }

    auto aFrag = [&](int kchunk) -> short8 {
        const int k0 = kchunk * 32 + quad * 8;
        const __hip_bfloat16* sp;
        if constexpr (AMODE == A_PLAIN) {
            sp = A + (size_t)rc * lda + k0;
        } else if constexpr (AMODE == A_FEAT) {
            if (k0 < L)          sp = n16  + (size_t)sI * L + k0;
            else if (k0 < 2 * L) sp = n16  + (size_t)rI * L + (k0 - L);
            else                 sp = e16s + (size_t)rc * L + (k0 - 2 * L);
        } else {
            if (k0 < L) sp = n16   + (size_t)rc * L + k0;
            else        sp = agg16 + (size_t)rc * L + (k0 - L);
        }
        return *(const short8*)sp;
    };
    auto loadW = [&](const __hip_bfloat16* secPtr, int ch, int4* wr) {
        #pragma unroll
        for (int it = 0; it < 4; it++)
            if (it < 2 * ch)
                wr[it] = *(const int4*)(secPtr + (size_t)wv * ch * 1024 + it * 512 + lane * 8);
    };
    auto storeW = [&](int buf, int ch, const int4* wr) {
        #pragma unroll
        for (int it = 0; it < 4; it++)
            if (it < 2 * ch)
                *(int4*)(wbuf + buf * 16384 + wv * ch * 2048 + it * 1024 + lane * 16) = wr[it];
    };
    auto bread = [&](int buf, int kc, int ct) -> short8 {
        return *(const short8*)(wbuf + buf * 16384 + kc * 8192 + ct * 1024 + lane * 16);
    };

    constexpr int CH0 = (K0 == 32) ? 1 : 2;
    constexpr int S0  = (K0 == 32) ? 1 : (K0 / 64);

    int4 wreg[4];
    short8 aF[2];
    int buf = 0;
    floatx4 acc[8];

    // ===================== layer 0 =====================
    #pragma unroll
    for (int ct = 0; ct < 8; ct++) acc[ct] = (floatx4)0.f;

    loadW(WT0, CH0, wreg);
    aF[0] = aFrag(0);
    if constexpr (CH0 == 2) aF[1] = aFrag(1);

    for (int sec = 0; sec < S0; sec++) {
        storeW(buf, CH0, wreg);
        __syncthreads();
        const short8 a0 = aF[0];
        const short8 a1 = aF[1];
        if (sec + 1 < S0) {
            loadW(WT0 + (size_t)(sec + 1) * CH0 * 4096, CH0, wreg);
            aF[0] = aFrag((sec + 1) * CH0);
            if constexpr (CH0 == 2) aF[1] = aFrag((sec + 1) * CH0 + 1);
        } else {
            loadW(WT1, 2, wreg);      // chain: layer-1 section 0
        }
        #pragma unroll
        for (int ct = 0; ct < 8; ct++)
            acc[ct] = __builtin_amdgcn_mfma_f32_16x16x32_bf16(a0, bread(buf, 0, ct), acc[ct], 0, 0, 0);
        if constexpr (CH0 == 2) {
            #pragma unroll
            for (int ct = 0; ct < 8; ct++)
                acc[ct] = __builtin_amdgcn_mfma_f32_16x16x32_bf16(a1, bread(buf, 1, ct), acc[ct], 0, 0, 0);
        }
        buf ^= 1;
    }
    {
        float bb[8];
        #pragma unroll
        for (int ct = 0; ct < 8; ct++) bb[ct] = ldmix(b0, poff + ct * 16 + m15, isf32);
        #pragma unroll
        for (int ct = 0; ct < 8; ct++)
            #pragma unroll
            for (int i = 0; i < 4; i++) {
                const int rl = quad * 4 + i;
                const int col = ct * 16 + m15;
                *(__hip_bfloat16*)(hw + rl * H_STRIDE + col * 2) =
                    __float2bfloat16(fmaxf(acc[ct][i] + bb[ct], 0.f));
            }
    }

    // ===================== layer 1 =====================
    {
        #pragma unroll
        for (int ct = 0; ct < 8; ct++) acc[ct] = (floatx4)0.f;
        short8 af[4];
        #pragma unroll
        for (int c = 0; c < 4; c++)
            af[c] = *(const short8*)(hw + m15 * H_STRIDE + c * 64 + quad * 16);
        for (int sec = 0; sec < 2; sec++) {
            storeW(buf, 2, wreg);
            __syncthreads();
            if (sec == 0)            loadW(WT1 + 8192, 2, wreg);
            else if constexpr (NL == 3) loadW(WT2, 2, wreg);
            #pragma unroll
            for (int kc = 0; kc < 2; kc++)
                #pragma unroll
                for (int ct = 0; ct < 8; ct++)
                    acc[ct] = __builtin_amdgcn_mfma_f32_16x16x32_bf16(
                        af[sec * 2 + kc], bread(buf, kc, ct), acc[ct], 0, 0, 0);
            buf ^= 1;
        }
        float bb[8];
        #pragma unroll
        for (int ct = 0; ct < 8; ct++) bb[ct] = ldmix(b1, poff + ct * 16 + m15, isf32);
        #pragma unroll
        for (int ct = 0; ct < 8; ct++)
            #pragma unroll
            for (int i = 0; i < 4; i++) {
                const int rl = quad * 4 + i;
                const int col = ct * 16 + m15;
                *(__hip_bfloat16*)(hw + rl * H_STRIDE + col * 2) =
                    __float2bfloat16(fmaxf(acc[ct][i] + bb[ct], 0.f));
            }
    }

    if constexpr (NL == 3) {
        // ===================== layer 2 + LN epilogue =====================
        #pragma unroll
        for (int ct = 0; ct < 8; ct++) acc[ct] = (floatx4)0.f;
        short8 af[4];
        #pragma unroll
        for (int c = 0; c < 4; c++)
            af[c] = *(const short8*)(hw + m15 * H_STRIDE + c * 64 + quad * 16);
        for (int sec = 0; sec < 2; sec++) {
            storeW(buf, 2, wreg);
            __syncthreads();
            if (sec == 0) loadW(WT2 + 8192, 2, wreg);
            #pragma unroll
            for (int kc = 0; kc < 2; kc++)
                #pragma unroll
                for (int ct = 0; ct < 8; ct++)
                    acc[ct] = __builtin_amdgcn_mfma_f32_16x16x32_bf16(
                        af[sec * 2 + kc], bread(buf, kc, ct), acc[ct], 0, 0, 0);
            buf ^= 1;
        }
        float bb[8], gg[8], be[8];
        #pragma unroll
        for (int ct = 0; ct < 8; ct++) {
            bb[ct] = ldmix(b2,   poff + ct * 16 + m15, isf32);
            gg[ct] = ldmix(g,    poff + ct * 16 + m15, isf32);
            be[ct] = ldmix(beta, poff + ct * 16 + m15, isf32);
        }
        #pragma unroll
        for (int i = 0; i < 4; i++) {
            float t[8], s = 0.f, s2 = 0.f;
            #pragma unroll
            for (int ct = 0; ct < 8; ct++) {
                t[ct] = acc[ct][i] + bb[ct];
                s  += t[ct];
                s2 += t[ct] * t[ct];
            }
            #pragma unroll
            for (int m = 1; m < 16; m <<= 1) {
                s  += __shfl_xor(s,  m, 64);
                s2 += __shfl_xor(s2, m, 64);
            }
            const float mean = s * (1.f / 128.f);
            const float var  = s2 * (1.f / 128.f) - mean * mean;
            const float inv  = rsqrtf(fmaxf(var, 0.f) + LN_EPS);
            const int rg = row0 + wv * 16 + quad * 4 + i;
            if (rg < M) {
                #pragma unroll
                for (int ct = 0; ct < 8; ct++) {
                    const int col = ct * 16 + m15;
                    const float o = (t[ct] - mean) * inv * gg[ct] + be[ct];
                    const size_t idx = (size_t)rg * L + col;
                    if constexpr (EPI == E_LN_STORE) {
                        res32[idx] = o;
                        if (res16) res16[idx] = __float2bfloat16(o);
                    } else if constexpr (EPI == E_LN_NODE) {
                        const float nw = res32[idx] + o;
                        res32[idx] = nw;
                        res16[idx] = __float2bfloat16(nw);
                    } else { // E_LN_EDGE
                        const float nw = res32[idx] + o;
                        res32[idx] = nw;
                        res16[idx] = __float2bfloat16(nw);
                        lnout[idx] = __float2bfloat16(o);
                    }
                }
            }
        }
    } else {
        // ===================== decoder head =====================
        __syncthreads();
        float* Wl = (float*)wbuf;
        for (int i = tid; i < 3 * L; i += NTHR) {
            const int o = i / L, k = i - o * L;
            Wl[o * L + k] = ldmix(dW, k * 3 + o, isf32);
        }
        __syncthreads();
        if (tid < 64) {
            const int rg = row0 + tid;
            if (rg < M) {
                const __hip_bfloat16* hr =
                    (const __hip_bfloat16*)(lds + (tid >> 4) * 4352 + (tid & 15) * H_STRIDE);
                float s0 = ldmix(db, 0, isf32);
                float s1 = ldmix(db, 1, isf32);
                float s2 = ldmix(db, 2, isf32);
                #pragma unroll 8
                for (int k = 0; k < L; k++) {
                    const float hv = bf2f(hr[k]);
                    s0 += hv * Wl[k];
                    s1 += hv * Wl[L + k];
                    s2 += hv * Wl[2 * L + k];
                }
                if (isf32) {
                    float* o = (float*)dout;
                    o[rg * 3 + 0] = s0; o[rg * 3 + 1] = s1; o[rg * 3 + 2] = s2;
                } else {
                    __hip_bfloat16* o = (__hip_bfloat16*)dout;
                    o[rg * 3 + 0] = __float2bfloat16(s0);
                    o[rg * 3 + 1] = __float2bfloat16(s1);
                    o[rg * 3 + 2] = __float2bfloat16(s2);
                }
            }
        }
    }
}

// ---------------------------------------------------------------------------
extern "C" void kernel_launch(void* const* d_in, const int* in_sizes, int n_in,
                              void* d_out, int out_size, void* d_ws, size_t ws_size,
                              hipStream_t stream)
{
    (void)in_sizes; (void)n_in; (void)out_size; (void)ws_size;
    const int* snd = (const int*)d_in[2];
    const int* rcv = (const int*)d_in[3];

    char* ws = (char*)d_ws;
    int* cnt = (int*)ws;                              ws += 256;
    auto takeB = [&](size_t el) {
        __hip_bfloat16* p = (__hip_bfloat16*)ws;
        ws += ((el * 2 + 255) & ~255ull);
        return p;
    };
    auto takeF = [&](size_t el) {
        float* p = (float*)ws;
        ws += ((el * 4 + 255) & ~255ull);
        return p;
    };
    auto takeI = [&](size_t el) {
        int* p = (int*)ws;
        ws += ((el * 4 + 255) & ~255ull);
        return p;
    };

    const int srcIdx[N_TMATS] = {4, 6, 8, 12, 14, 16, 20, 22, 24, 28, 30, 32, 36, 38};
    const int tK[N_TMATS]    = {12, 128, 128, 7, 128, 128, 384, 128, 128, 256, 128, 128, 128, 128};
    const int tKp[N_TMATS]   = {32, 128, 128, 32, 128, 128, 384, 128, 128, 256, 128, 128, 128, 128};
    const int tNm[N_TMATS]   = {1, 1, 1, 1, 1, 1, STEPS, STEPS, STEPS, STEPS, STEPS, STEPS, 1, 1};
    TAll ta;
    long long cum = 0;
    __hip_bfloat16* wmat[N_TMATS];
    __hip_bfloat16* wpool = (__hip_bfloat16*)ws;
    for (int j = 0; j < N_TMATS; j++) {
        ta.src[j] = d_in[srcIdx[j]];
        ta.cum[j] = cum;
        ta.K[j] = tK[j]; ta.N[j] = 128; ta.Kpad[j] = tKp[j];
        wmat[j] = wpool + cum;
        cum += (long long)tNm[j] * 128 * tKp[j];
    }
    ta.cum[N_TMATS] = cum;
    ws += ((cum * 2 + 255) & ~255ull);

    float* n32 = takeF((size_t)N_NODES * L);
    float* e32 = takeF((size_t)N_EDGES * L);
    __hip_bfloat16* n16   = takeB((size_t)N_NODES * L);
    __hip_bfloat16* e16   = takeB((size_t)N_EDGES * L);
    __hip_bfloat16* ln16  = takeB((size_t)N_EDGES * L);
    __hip_bfloat16* agg16 = takeB((size_t)N_NODES * L);
    __hip_bfloat16* fN16  = takeB((size_t)N_NODES * 32);
    __hip_bfloat16* fE16  = takeB((size_t)N_EDGES * 32);
    int* deg    = takeI(N_NODES);
    int* rowptr = takeI(N_NODES + 1);
    int* cursor = takeI(N_NODES);
    int* elist  = takeI(N_EDGES);
    int* ssnd   = takeI(N_EDGES);
    int* srcv   = takeI(N_EDGES);

    const dim3 blk(NTHR);
    const dim3 grdE((N_EDGES + 63) / 64);     // 1250
    const dim3 grdN((N_NODES + 63) / 64);     // 157

    (void)hipMemsetAsync(cnt, 0, sizeof(int), stream);
    (void)hipMemsetAsync(deg, 0, N_NODES * sizeof(int), stream);
    detect_dtype<<<dim3(64), blk, 0, stream>>>((const uint32_t*)d_in[0], cnt);
    transpose_all<<<dim3(512), blk, 0, stream>>>(ta, cnt, wpool);

    csr_hist<<<dim3(80), blk, 0, stream>>>(rcv, deg);
    csr_scan<<<dim3(1), blk, 0, stream>>>(deg, rowptr, cursor);
    csr_scatter<<<dim3(80), blk, 0, stream>>>(rcv, cursor, elist);
    sort_meta<<<dim3(80), blk, 0, stream>>>(snd, rcv, elist, ssnd, srcv);
    convert_feats<<<dim3(256), blk, 0, stream>>>(d_in[0], d_in[1], cnt, elist, fN16, fE16);

    // ---- encoders (edge streams in sorted order) ----
    fused_mlp<A_PLAIN, E_LN_STORE, 3, 32><<<grdE, blk, 0, stream>>>(
        fE16, 32, N_EDGES, wmat[3], wmat[4], wmat[5],
        d_in[13], d_in[15], d_in[17], d_in[18], d_in[19], 0, cnt,
        nullptr, nullptr, nullptr, nullptr, nullptr,
        e32, e16, nullptr, nullptr, nullptr, nullptr);
    fused_mlp<A_PLAIN, E_LN_STORE, 3, 32><<<grdN, blk, 0, stream>>>(
        fN16, 32, N_NODES, wmat[0], wmat[1], wmat[2],
        d_in[5], d_in[7], d_in[9], d_in[10], d_in[11], 0, cnt,
        nullptr, nullptr, nullptr, nullptr, nullptr,
        n32, n16, nullptr, nullptr, nullptr, nullptr);

    // ---- processor ----
    for (int s = 0; s < STEPS; s++) {
        const int po = s * L;
        fused_mlp<A_FEAT, E_LN_EDGE, 3, 384><<<grdE, blk, 0, stream>>>(
            nullptr, 0, N_EDGES,
            wmat[6] + (size_t)s * 128 * 384,
            wmat[7] + (size_t)s * 128 * 128,
            wmat[8] + (size_t)s * 128 * 128,
            d_in[21], d_in[23], d_in[25], d_in[26], d_in[27], po, cnt,
            n16, e16, nullptr, ssnd, srcv,
            e32, e16, ln16, nullptr, nullptr, nullptr);
        csr_agg<<<dim3((N_NODES + 7) / 8), blk, 0, stream>>>(rowptr, ln16, agg16);
        fused_mlp<A_CAT, E_LN_NODE, 3, 256><<<grdN, blk, 0, stream>>>(
            nullptr, 0, N_NODES,
            wmat[9]  + (size_t)s * 128 * 256,
            wmat[10] + (size_t)s * 128 * 128,
            wmat[11] + (size_t)s * 128 * 128,
            d_in[29], d_in[31], d_in[33], d_in[34], d_in[35], po, cnt,
            n16, nullptr, agg16, nullptr, nullptr,
            n32, n16, nullptr, nullptr, nullptr, nullptr);
    }

    // ---- decoder ----
    fused_mlp<A_PLAIN, E_DEC, 2, 128><<<grdN, blk, 0, stream>>>(
        n16, 128, N_NODES, wmat[12], wmat[13], nullptr,
        d_in[37], d_in[39], nullptr, nullptr, nullptr, 0, cnt,
        nullptr, nullptr, nullptr, nullptr, nullptr,
        nullptr, nullptr, nullptr, d_in[40], d_in[41], d_out);
}